// Round 6
// baseline (335.412 us; speedup 1.0000x reference)
//
#include <hip/hip_runtime.h>
#include <stdint.h>

#define B_ 64
#define T_ 4096
#define D_ 90
#define K_ 32
#define CH_ 32   // chunk length (R6: 256 -> 32; 8192 waves = 8/SIMD for latency hiding)
#define F_  128  // number of T-chunks = T_/CH_

typedef float f32x16 __attribute__((ext_vector_type(16)));
typedef __bf16 bf16x8 __attribute__((ext_vector_type(8)));

// ---- workspace layout (float offsets). total 12603456 floats = 50.4 MB ----
#define WS_A     0          // 1024 : softmax(transition) rows, A[j*32+k]
#define WS_PI    1024       // 32   : softmax(priors)
#define WS_C0    1056       // 32   : per-state emission constant
#define WS_WF    1088       // 6144 bf16 : MFMA B-fragments of emission weights
#define WS_EACC  4160       // 8192 ints : per-(b,chunk) renorm exponent
#define WS_MS    12352      // 8192 : per-wave msum slots (R3: contended atomics ~12ns/op — never again)
#define WS_E     20544      // 8388608 bf16 : E^T[b][k][t] = exp(em - m_t)
#define WS_Q     4214848    // 8388608 : Q[b][c][k_new][j_old]

// block-swap involution: swap 4-7<->8-11 and 20-23<->24-27
__device__ __forceinline__ int perm_r(int r) {
  int t2 = (r >> 2) & 3;
  return r + ((t2 == 1) ? 4 : (t2 == 2) ? -4 : 0);
}
// pack two f32 -> bf16x2 dword, truncation — single v_perm_b32 (R6: was and+lshr+or)
__device__ __forceinline__ uint32_t pk2(float hi, float lo) {
  return __builtin_amdgcn_perm(__float_as_uint(hi), __float_as_uint(lo), 0x07060302u);
}
// round-to-nearest variant (emission path)
__device__ __forceinline__ uint32_t rnd_pk(float hi, float lo) {
  uint32_t uh = __float_as_uint(hi) + 0x8000u;
  uint32_t ul = __float_as_uint(lo) + 0x8000u;
  return __builtin_amdgcn_perm(uh, ul, 0x07060302u);
}
__device__ __forceinline__ float bf2f(ushort u) {
  return __uint_as_float(((uint32_t)u) << 16);
}
__device__ __forceinline__ bf16x8 mkbf(uint32_t a, uint32_t b, uint32_t c, uint32_t d) {
  union { uint32_t u[4]; bf16x8 v; } x;
  x.u[0] = a; x.u[1] = b; x.u[2] = c; x.u[3] = d;
  return x.v;
}

// ---------------- prep: softmaxes + emission weight fragments ----------------
__global__ __launch_bounds__(1024) void prep_kernel(
    const float* __restrict__ priors, const float* __restrict__ trans,
    const float* __restrict__ mu, const float* __restrict__ lv,
    float* __restrict__ ws) {
  int tid = threadIdx.x;
  {  // transition row softmax: tid = j*32+k, 32-lane groups are rows
    float v = trans[tid];
    float m = v;
    #pragma unroll
    for (int mk = 16; mk; mk >>= 1) m = fmaxf(m, __shfl_xor(m, mk));
    float e = expf(v - m);
    float s = e;
    #pragma unroll
    for (int mk = 16; mk; mk >>= 1) s += __shfl_xor(s, mk);
    ws[WS_A + tid] = e / s;
  }
  if (tid < 32) {  // prior softmax
    float v = priors[tid];
    float m = v;
    #pragma unroll
    for (int mk = 16; mk; mk >>= 1) m = fmaxf(m, __shfl_xor(m, mk));
    float e = expf(v - m);
    float s = e;
    #pragma unroll
    for (int mk = 16; mk; mk >>= 1) s += __shfl_xor(s, mk);
    ws[WS_PI + tid] = e / s;
  }
  // MFMA B-operand weight fragments, bf16, layout [c][mat][lane][j]
  // element = W[d = 16c + 8(lane>>5) + j][k = lane&31]; mat0 = -0.5*iv (x^2), mat1 = mu*iv (x)
  for (int i = tid; i < 6144; i += 1024) {
    int j = i & 7, l = (i >> 3) & 63, cm = i >> 9;
    int c = cm >> 1, mat = cm & 1;
    int h = l >> 5, nn = l & 31;
    int d = 16 * c + 8 * h + j;
    float v = 0.0f;
    if (d < D_) {
      float ivd = expf(-lv[nn * D_ + d]);
      v = (mat == 0) ? -0.5f * ivd : mu[nn * D_ + d] * ivd;
    }
    ((ushort*)(ws + WS_WF))[i] = (ushort)((__float_as_uint(v) + 0x8000u) >> 16);
  }
  if (tid < 32) {  // c0[k] = -0.5*(sum mu^2*iv + sum lv + D*log(2pi))
    float s = 0.0f;
    for (int d = 0; d < D_; ++d) {
      float l  = lv[tid * D_ + d];
      float iv = expf(-l);
      float m_ = mu[tid * D_ + d];
      s += m_ * m_ * iv + l;
    }
    ws[WS_C0 + tid] = -0.5f * (s + (float)D_ * 1.8378770664093453f);
  }
}

// ---------------- emission via MFMA: E^T[b][k][t] = exp(em - m_t) (bf16) ----------------
// LDS-staged X (coalesced float4), then per-wave 32-t tile, 12 mfma_32x32x16_bf16.
__global__ __launch_bounds__(256) void emis_kernel(const float* __restrict__ X,
                                                   float* __restrict__ ws) {
  __shared__ float xs[4 * 2888];     // 4 wave-regions of 32 rows x 90 (+8 pad)
  int tid = threadIdx.x;
  int l = tid & 63;
  int w = tid >> 6;
  int n = l & 31, h = l >> 5;
  int tB = blockIdx.x << 7;          // block covers 128 contiguous rows
  const float4* Xg = (const float4*)(X + (size_t)tB * D_);
  #pragma unroll
  for (int it = 0; it < 12; ++it) {
    int i = tid + (it << 8);
    if (i < 2880) {
      int g = i / 720;               // 32-row group
      ((float4*)xs)[g * 722 + (i - g * 720)] = Xg[i];
    }
  }
  const uint4* wfp = (const uint4*)((const ushort*)(ws + WS_WF));
  uint4 wf[12];
  #pragma unroll
  for (int cm = 0; cm < 12; ++cm) wf[cm] = wfp[cm * 64 + l];   // coalesced b128
  float c0 = ws[WS_C0 + n];
  __syncthreads();
  int t0 = tB + (w << 5);
  int b  = t0 >> 12;
  const float* xrow = xs + w * 2888 + n * 90;       // A-row m = n
  f32x16 acc1, acc2;
  #pragma unroll
  for (int r = 0; r < 16; ++r) { acc1[r] = 0.0f; acc2[r] = 0.0f; }
  #pragma unroll
  for (int c = 0; c < 6; ++c) {
    float x[8];
    int s = 16 * c + 8 * h;                          // kk = d = s + j
    const float2* p = (const float2*)(xrow + s);     // 8B-aligned, 2-way bank alias (free)
    #pragma unroll
    for (int r = 0; r < 4; ++r) { float2 v = p[r]; x[2*r] = v.x; x[2*r+1] = v.y; }
    if (c == 5) {                                    // zero padded d >= 90
      #pragma unroll
      for (int j = 0; j < 8; ++j) if (s + j >= D_) x[j] = 0.0f;
    }
    union { uint32_t u[4]; bf16x8 v; } xb, x2b;
    #pragma unroll
    for (int r = 0; r < 4; ++r) {
      xb.u[r]  = rnd_pk(x[2*r+1], x[2*r]);
      x2b.u[r] = rnd_pk(x[2*r+1] * x[2*r+1], x[2*r] * x[2*r]);
    }
    union { uint4 u; bf16x8 v; } w2, w1;
    w2.u = wf[c * 2]; w1.u = wf[c * 2 + 1];
    acc1 = __builtin_amdgcn_mfma_f32_32x32x16_bf16(xb.v,  w1.v, acc1, 0, 0, 0);
    acc2 = __builtin_amdgcn_mfma_f32_32x32x16_bf16(x2b.v, w2.v, acc2, 0, 0, 0);
  }
  // C/D: col k = n, row t = (r&3) + 8*(r>>2) + 4*h
  float em[16], mrow[16];
  #pragma unroll
  for (int r = 0; r < 16; ++r) {
    float v = acc1[r] + acc2[r] + c0;
    em[r] = v;
    float m = v;
    #pragma unroll
    for (int mk = 1; mk <= 16; mk <<= 1) m = fmaxf(m, __shfl_xor(m, mk));  // max over k
    mrow[r] = m;
  }
  ushort* Ew = (ushort*)(ws + WS_E);
  size_t ebase = (size_t)(b * K_ + n) * T_ + (t0 & (T_ - 1));
  #pragma unroll
  for (int q = 0; q < 4; ++q) {  // regs 4q..4q+3 are consecutive t's: pack 4 bf16 -> 8B store
    float e0 = exp2f((em[4*q]   - mrow[4*q])   * 1.44269504088896f);
    float e1 = exp2f((em[4*q+1] - mrow[4*q+1]) * 1.44269504088896f);
    float e2 = exp2f((em[4*q+2] - mrow[4*q+2]) * 1.44269504088896f);
    float e3 = exp2f((em[4*q+3] - mrow[4*q+3]) * 1.44269504088896f);
    uint2 d;
    d.x = rnd_pk(e1, e0);
    d.y = rnd_pk(e3, e2);
    *(uint2*)(Ew + ebase + 8 * q + 4 * h) = d;
  }
  float msum = 0.0f;
  #pragma unroll
  for (int r = 0; r < 16; ++r) msum += mrow[r];
  msum += __shfl_xor(msum, 32);                      // both halves' 16 rows
  if (l == 0) ws[WS_MS + (t0 >> 5)] = msum;          // private slot, plain store
}

// ---------------- phase 1: per-(b,chunk) transfer matrix via MFMA ----------------
// 32 steps per chunk; 2 independent waves per block; E loads vectorized (uint4 = 8 steps).
__global__ __launch_bounds__(128) void chunk_kernel(float* __restrict__ ws) {
  int l = threadIdx.x & 63;
  int h = l >> 5, n = l & 31;
  int bc = (blockIdx.x << 1) | (threadIdx.x >> 6);   // 0..8191
  int b = bc >> 7, c = bc & (F_ - 1);
  int col = perm_r(n);                // logical output-state of this lane's A column
  const float* A = ws + WS_A;
  float astat[16];                    // A[s][col] for s = 8h+j and 16+8h+j
  #pragma unroll
  for (int j = 0; j < 8; ++j) {
    astat[j]     = A[(8 * h + j) * K_ + col];
    astat[8 + j] = A[(16 + 8 * h + j) * K_ + col];
  }
  uint32_t q[8];                      // Q fragments (bf16x2 dwords), init = I
  #pragma unroll
  for (int r = 0; r < 4; ++r) {
    int s0 = 8 * h + 2 * r;
    uint32_t lo = (s0 == n)     ? 0x3F80u : 0u;
    uint32_t hi = (s0 + 1 == n) ? 0x3F80u : 0u;
    q[r] = lo | (hi << 16);
    int s2 = s0 + 16;
    lo = (s2 == n)     ? 0x3F80u : 0u;
    hi = (s2 + 1 == n) ? 0x3F80u : 0u;
    q[4 + r] = lo | (hi << 16);
  }
  const ushort* Eb = (const ushort*)(ws + WS_E) + (size_t)(b * K_ + col) * T_ + c * CH_;
  int eacc = 0;
  const f32x16 z = {0.f,0.f,0.f,0.f,0.f,0.f,0.f,0.f,0.f,0.f,0.f,0.f,0.f,0.f,0.f,0.f};
  f32x16 acc;
  #pragma unroll
  for (int r = 0; r < 16; ++r) acc[r] = 0.0f;

  auto step = [&](float e0) {
    uint32_t au[8];
    #pragma unroll
    for (int r = 0; r < 4; ++r) {     // A-frag = astat * E[col], truncated to bf16
      au[r]     = pk2(astat[2 * r + 1] * e0, astat[2 * r] * e0);
      au[4 + r] = pk2(astat[8 + 2 * r + 1] * e0, astat[8 + 2 * r] * e0);
    }
    bf16x8 alo = mkbf(au[0], au[1], au[2], au[3]);
    bf16x8 ahi = mkbf(au[4], au[5], au[6], au[7]);
    bf16x8 qlo = mkbf(q[0], q[1], q[2], q[3]);
    bf16x8 qhi = mkbf(q[4], q[5], q[6], q[7]);
    acc = __builtin_amdgcn_mfma_f32_32x32x16_bf16(alo, qlo, z, 0, 0, 0);
    acc = __builtin_amdgcn_mfma_f32_32x32x16_bf16(ahi, qhi, acc, 0, 0, 0);
    #pragma unroll
    for (int r = 0; r < 4; ++r) {     // D regs -> next B-frag, in-lane repack only
      q[r]     = pk2(acc[2 * r + 1], acc[2 * r]);
      q[4 + r] = pk2(acc[8 + 2 * r + 1], acc[8 + 2 * r]);
    }
  };
  auto renorm = [&]() {               // exact power-of-2 renormalization
    float m = acc[0];
    #pragma unroll
    for (int r = 1; r < 16; ++r) m = fmaxf(m, acc[r]);
    #pragma unroll
    for (int mk = 1; mk <= 32; mk <<= 1) m = fmaxf(m, __shfl_xor(m, mk));
    int ex;
    frexpf(m, &ex);
    float sc = ldexpf(1.0f, -ex);
    eacc += ex;
    #pragma unroll
    for (int r = 0; r < 16; ++r) acc[r] *= sc;
    #pragma unroll
    for (int r = 0; r < 4; ++r) {     // re-pack q from renormalized acc
      q[r]     = pk2(acc[2 * r + 1], acc[2 * r]);
      q[4 + r] = pk2(acc[8 + 2 * r + 1], acc[8 + 2 * r]);
    }
  };

  uint4 ev = *(const uint4*)(Eb);     // group 0 (8 steps of E, 16B)
  int gstart = 0;
  if (c == 0) {                       // t=0 is the prior step: skip it
    uint4 evn = *(const uint4*)(Eb + 8);
    #pragma unroll
    for (int j = 1; j < 8; ++j) {
      uint32_t u = ((const uint32_t*)&ev)[j >> 1];
      step(bf2f((j & 1) ? (ushort)(u >> 16) : (ushort)(u & 0xFFFF)));
    }
    renorm();
    ev = evn;
    gstart = 1;
  }
  for (int g = gstart; g < CH_ / 8; ++g) {
    uint4 evn;
    if (g < CH_ / 8 - 1) evn = *(const uint4*)(Eb + 8 * (g + 1));  // prefetch next group
    #pragma unroll
    for (int j = 0; j < 8; ++j) {
      uint32_t u = ((const uint32_t*)&ev)[j >> 1];
      step(bf2f((j & 1) ? (ushort)(u >> 16) : (ushort)(u & 0xFFFF)));
    }
    renorm();
    ev = evn;
  }
  float* Qout = ws + WS_Q + (size_t)bc * (K_ * K_);
  #pragma unroll
  for (int r = 0; r < 16; ++r) {      // store un-permuted: row = pi(physical row)
    int m_ = (r & 3) + 8 * (r >> 2) + 4 * h;
    Qout[perm_r(m_) * K_ + n] = acc[r];
  }
  if (l == 0) ((int*)ws)[WS_EACC + bc] = eacc;
}

// ---------------- phase 2: sequential combine of 128 chunk matrices per b ----------------
// lane 2k+half holds Q[k][16*half..+15] in registers; depth-8 prefetch ring;
// renorm every 4 iterations (growth <= 2^20 per window — fp32-safe, verified R5).
__global__ __launch_bounds__(64) void combine_kernel(float* __restrict__ ws,
                                                     float* __restrict__ out) {
  int l = threadIdx.x;
  int b = blockIdx.x;
  int half = l & 1;
  const ushort* Ew = (const ushort*)(ws + WS_E);
  float alpha = 0.0f;
  if (l < 32) alpha = ws[WS_PI + l] * bf2f(Ew[(size_t)(b * K_ + l) * T_]);
  // msum reduction: 128 slots for this b
  float msm = ws[WS_MS + b * 128 + l] + ws[WS_MS + b * 128 + 64 + l];
  #pragma unroll
  for (int mk = 32; mk; mk >>= 1) msm += __shfl_xor(msm, mk);
  int escale = 0;
  const int* eaccs = ((const int*)ws) + WS_EACC + b * F_;
  const float4* Qb = (const float4*)(ws + WS_Q + (size_t)b * (F_ * K_ * K_));
  float4 buf[8][4];
  #pragma unroll
  for (int p = 0; p < 8; ++p)
    #pragma unroll
    for (int i = 0; i < 4; ++i) buf[p][i] = Qb[p * 256 + l * 4 + i];
  for (int c = 0; c < F_; ++c) {
    int pb = c & 7;
    float s0 = 0.0f, s1 = 0.0f;        // split dot chain to halve fma latency
    #pragma unroll
    for (int i = 0; i < 8; ++i) {
      float aj = __shfl(alpha, 16 * half + i);
      s0 = fmaf(aj, ((const float*)&buf[pb][0])[i], s0);
    }
    #pragma unroll
    for (int i = 8; i < 16; ++i) {
      float aj = __shfl(alpha, 16 * half + i);
      s1 = fmaf(aj, ((const float*)&buf[pb][0])[i], s1);
    }
    float s = s0 + s1;
    if (c + 8 < F_) {                  // depth-8 prefetch into the buffer just consumed
      #pragma unroll
      for (int i = 0; i < 4; ++i) buf[pb][i] = Qb[(c + 8) * 256 + l * 4 + i];
    }
    s += __shfl_xor(s, 1);             // combine j-halves: lanes 2k,2k+1 hold alpha'[k]
    if ((c & 3) == 3) {                // renorm every 4 iterations
      float mm = s;
      #pragma unroll
      for (int mk = 2; mk <= 32; mk <<= 1) mm = fmaxf(mm, __shfl_xor(mm, mk));
      int ex;
      frexpf(mm, &ex);
      s = ldexpf(s, -ex);
      escale += ex;
    }
    escale += eaccs[c];
    alpha = __shfl(s, (l & 31) * 2);   // lane j <- alpha'[j]
  }
  if (l < 32) {
    float ssum = alpha;
    #pragma unroll
    for (int mk = 16; mk; mk >>= 1) ssum += __shfl_xor(ssum, mk);
    if (l == 0) {
      float res = logf(ssum) + (float)escale * 0.69314718055994531f + msm;
      atomicAdd(out, res);
    }
  }
}

extern "C" void kernel_launch(void* const* d_in, const int* in_sizes, int n_in,
                              void* d_out, int out_size, void* d_ws, size_t ws_size,
                              hipStream_t stream) {
  (void)in_sizes; (void)n_in; (void)out_size; (void)ws_size;
  const float* X      = (const float*)d_in[0];
  const float* priors = (const float*)d_in[1];
  const float* trans  = (const float*)d_in[2];
  const float* mu     = (const float*)d_in[3];
  const float* lv     = (const float*)d_in[4];
  float* ws  = (float*)d_ws;
  float* out = (float*)d_out;
  hipMemsetAsync(out, 0, sizeof(float), stream);
  prep_kernel<<<1, 1024, 0, stream>>>(priors, trans, mu, lv, ws);
  emis_kernel<<<2048, 256, 0, stream>>>(X, ws);
  chunk_kernel<<<B_ * F_ / 2, 128, 0, stream>>>(ws);
  combine_kernel<<<B_, 64, 0, stream>>>(ws, out);
}

// Round 7
// 211.038 us; speedup vs baseline: 1.5893x; 1.5893x over previous
//
#include <hip/hip_runtime.h>
#include <stdint.h>

#define B_ 64
#define T_ 4096
#define D_ 90
#define K_ 32
#define CH_ 32   // chunk length (8192 waves = 8/SIMD for latency hiding)
#define F_  128  // number of T-chunks = T_/CH_

typedef float f32x16 __attribute__((ext_vector_type(16)));
typedef __bf16 bf16x8 __attribute__((ext_vector_type(8)));

// ---- workspace layout (float offsets). total 12603456 floats = 50.4 MB ----
#define WS_A     0          // 1024 : softmax(transition) rows, A[j*32+k]
#define WS_PI    1024       // 32   : softmax(priors)
#define WS_C0    1056       // 32   : per-state emission constant
#define WS_WF    1088       // 6144 bf16 : MFMA B-fragments of emission weights
#define WS_EACC  4160       // 8192 ints : per-(b,chunk) renorm exponent
#define WS_MS    12352      // 8192 : per-wave msum slots (R3: contended atomics ~12ns/op — never again)
#define WS_E     20544      // 8388608 bf16 : E^T[b][k][t] = exp(em - m_t)
#define WS_Q     4214848    // 8388608 : Q[b][c][k_new][j_old] fp32

// block-swap involution: swap 4-7<->8-11 and 20-23<->24-27
__device__ __forceinline__ int perm_r(int r) {
  int t2 = (r >> 2) & 3;
  return r + ((t2 == 1) ? 4 : (t2 == 2) ? -4 : 0);
}
// pack two f32 -> bf16x2 dword, truncation — single v_perm_b32
__device__ __forceinline__ uint32_t pk2(float hi, float lo) {
  return __builtin_amdgcn_perm(__float_as_uint(hi), __float_as_uint(lo), 0x07060302u);
}
// round-to-nearest variant (emission path)
__device__ __forceinline__ uint32_t rnd_pk(float hi, float lo) {
  uint32_t uh = __float_as_uint(hi) + 0x8000u;
  uint32_t ul = __float_as_uint(lo) + 0x8000u;
  return __builtin_amdgcn_perm(uh, ul, 0x07060302u);
}
__device__ __forceinline__ float bf2f(ushort u) {
  return __uint_as_float(((uint32_t)u) << 16);
}
__device__ __forceinline__ bf16x8 mkbf(uint32_t a, uint32_t b, uint32_t c, uint32_t d) {
  union { uint32_t u[4]; bf16x8 v; } x;
  x.u[0] = a; x.u[1] = b; x.u[2] = c; x.u[3] = d;
  return x.v;
}

// ---------------- prep: softmaxes + emission weight fragments ----------------
__global__ __launch_bounds__(1024) void prep_kernel(
    const float* __restrict__ priors, const float* __restrict__ trans,
    const float* __restrict__ mu, const float* __restrict__ lv,
    float* __restrict__ ws) {
  int tid = threadIdx.x;
  {  // transition row softmax: tid = j*32+k, 32-lane groups are rows
    float v = trans[tid];
    float m = v;
    #pragma unroll
    for (int mk = 16; mk; mk >>= 1) m = fmaxf(m, __shfl_xor(m, mk));
    float e = expf(v - m);
    float s = e;
    #pragma unroll
    for (int mk = 16; mk; mk >>= 1) s += __shfl_xor(s, mk);
    ws[WS_A + tid] = e / s;
  }
  if (tid < 32) {  // prior softmax
    float v = priors[tid];
    float m = v;
    #pragma unroll
    for (int mk = 16; mk; mk >>= 1) m = fmaxf(m, __shfl_xor(m, mk));
    float e = expf(v - m);
    float s = e;
    #pragma unroll
    for (int mk = 16; mk; mk >>= 1) s += __shfl_xor(s, mk);
    ws[WS_PI + tid] = e / s;
  }
  // MFMA B-operand weight fragments, bf16, layout [c][mat][lane][j]
  for (int i = tid; i < 6144; i += 1024) {
    int j = i & 7, l = (i >> 3) & 63, cm = i >> 9;
    int c = cm >> 1, mat = cm & 1;
    int h = l >> 5, nn = l & 31;
    int d = 16 * c + 8 * h + j;
    float v = 0.0f;
    if (d < D_) {
      float ivd = expf(-lv[nn * D_ + d]);
      v = (mat == 0) ? -0.5f * ivd : mu[nn * D_ + d] * ivd;
    }
    ((ushort*)(ws + WS_WF))[i] = (ushort)((__float_as_uint(v) + 0x8000u) >> 16);
  }
  if (tid < 32) {  // c0[k] = -0.5*(sum mu^2*iv + sum lv + D*log(2pi))
    float s = 0.0f;
    for (int d = 0; d < D_; ++d) {
      float l  = lv[tid * D_ + d];
      float iv = expf(-l);
      float m_ = mu[tid * D_ + d];
      s += m_ * m_ * iv + l;
    }
    ws[WS_C0 + tid] = -0.5f * (s + (float)D_ * 1.8378770664093453f);
  }
}

// ---------------- emission via MFMA: E^T[b][k][t] = exp(em - m_t) (bf16) ----------------
__global__ __launch_bounds__(256) void emis_kernel(const float* __restrict__ X,
                                                   float* __restrict__ ws) {
  __shared__ float xs[4 * 2888];     // 4 wave-regions of 32 rows x 90 (+8 pad)
  int tid = threadIdx.x;
  int l = tid & 63;
  int w = tid >> 6;
  int n = l & 31, h = l >> 5;
  int tB = blockIdx.x << 7;          // block covers 128 contiguous rows
  const float4* Xg = (const float4*)(X + (size_t)tB * D_);
  #pragma unroll
  for (int it = 0; it < 12; ++it) {
    int i = tid + (it << 8);
    if (i < 2880) {
      int g = i / 720;               // 32-row group
      ((float4*)xs)[g * 722 + (i - g * 720)] = Xg[i];
    }
  }
  const uint4* wfp = (const uint4*)((const ushort*)(ws + WS_WF));
  uint4 wf[12];
  #pragma unroll
  for (int cm = 0; cm < 12; ++cm) wf[cm] = wfp[cm * 64 + l];   // coalesced b128
  float c0 = ws[WS_C0 + n];
  __syncthreads();
  int t0 = tB + (w << 5);
  int b  = t0 >> 12;
  const float* xrow = xs + w * 2888 + n * 90;       // A-row m = n
  f32x16 acc1, acc2;
  #pragma unroll
  for (int r = 0; r < 16; ++r) { acc1[r] = 0.0f; acc2[r] = 0.0f; }
  #pragma unroll
  for (int c = 0; c < 6; ++c) {
    float x[8];
    int s = 16 * c + 8 * h;                          // kk = d = s + j
    const float2* p = (const float2*)(xrow + s);     // 8B-aligned, 2-way bank alias (free)
    #pragma unroll
    for (int r = 0; r < 4; ++r) { float2 v = p[r]; x[2*r] = v.x; x[2*r+1] = v.y; }
    if (c == 5) {                                    // zero padded d >= 90
      #pragma unroll
      for (int j = 0; j < 8; ++j) if (s + j >= D_) x[j] = 0.0f;
    }
    union { uint32_t u[4]; bf16x8 v; } xb, x2b;
    #pragma unroll
    for (int r = 0; r < 4; ++r) {
      xb.u[r]  = rnd_pk(x[2*r+1], x[2*r]);
      x2b.u[r] = rnd_pk(x[2*r+1] * x[2*r+1], x[2*r] * x[2*r]);
    }
    union { uint4 u; bf16x8 v; } w2, w1;
    w2.u = wf[c * 2]; w1.u = wf[c * 2 + 1];
    acc1 = __builtin_amdgcn_mfma_f32_32x32x16_bf16(xb.v,  w1.v, acc1, 0, 0, 0);
    acc2 = __builtin_amdgcn_mfma_f32_32x32x16_bf16(x2b.v, w2.v, acc2, 0, 0, 0);
  }
  // C/D: col k = n, row t = (r&3) + 8*(r>>2) + 4*h
  float em[16], mrow[16];
  #pragma unroll
  for (int r = 0; r < 16; ++r) {
    float v = acc1[r] + acc2[r] + c0;
    em[r] = v;
    float m = v;
    #pragma unroll
    for (int mk = 1; mk <= 16; mk <<= 1) m = fmaxf(m, __shfl_xor(m, mk));  // max over k
    mrow[r] = m;
  }
  ushort* Ew = (ushort*)(ws + WS_E);
  size_t ebase = (size_t)(b * K_ + n) * T_ + (t0 & (T_ - 1));
  #pragma unroll
  for (int q = 0; q < 4; ++q) {
    float e0 = exp2f((em[4*q]   - mrow[4*q])   * 1.44269504088896f);
    float e1 = exp2f((em[4*q+1] - mrow[4*q+1]) * 1.44269504088896f);
    float e2 = exp2f((em[4*q+2] - mrow[4*q+2]) * 1.44269504088896f);
    float e3 = exp2f((em[4*q+3] - mrow[4*q+3]) * 1.44269504088896f);
    uint2 d;
    d.x = rnd_pk(e1, e0);
    d.y = rnd_pk(e3, e2);
    *(uint2*)(Ew + ebase + 8 * q + 4 * h) = d;
  }
  float msum = 0.0f;
  #pragma unroll
  for (int r = 0; r < 16; ++r) msum += mrow[r];
  msum += __shfl_xor(msum, 32);                      // both halves' 16 rows
  if (l == 0) ws[WS_MS + (t0 >> 5)] = msum;          // private slot, plain store
}

// ---------------- phase 1: per-(b,chunk) transfer matrix via MFMA ----------------
__global__ __launch_bounds__(128) void chunk_kernel(float* __restrict__ ws) {
  int l = threadIdx.x & 63;
  int h = l >> 5, n = l & 31;
  int bc = (blockIdx.x << 1) | (threadIdx.x >> 6);   // 0..8191
  int b = bc >> 7, c = bc & (F_ - 1);
  int col = perm_r(n);                // logical output-state of this lane's A column
  const float* A = ws + WS_A;
  float astat[16];                    // A[s][col] for s = 8h+j and 16+8h+j
  #pragma unroll
  for (int j = 0; j < 8; ++j) {
    astat[j]     = A[(8 * h + j) * K_ + col];
    astat[8 + j] = A[(16 + 8 * h + j) * K_ + col];
  }
  uint32_t q[8];                      // Q fragments (bf16x2 dwords), init = I
  #pragma unroll
  for (int r = 0; r < 4; ++r) {
    int s0 = 8 * h + 2 * r;
    uint32_t lo = (s0 == n)     ? 0x3F80u : 0u;
    uint32_t hi = (s0 + 1 == n) ? 0x3F80u : 0u;
    q[r] = lo | (hi << 16);
    int s2 = s0 + 16;
    lo = (s2 == n)     ? 0x3F80u : 0u;
    hi = (s2 + 1 == n) ? 0x3F80u : 0u;
    q[4 + r] = lo | (hi << 16);
  }
  const ushort* Eb = (const ushort*)(ws + WS_E) + (size_t)(b * K_ + col) * T_ + c * CH_;
  int eacc = 0;
  const f32x16 z = {0.f,0.f,0.f,0.f,0.f,0.f,0.f,0.f,0.f,0.f,0.f,0.f,0.f,0.f,0.f,0.f};
  f32x16 acc;
  #pragma unroll
  for (int r = 0; r < 16; ++r) acc[r] = 0.0f;

  auto step = [&](float e0) {
    uint32_t au[8];
    #pragma unroll
    for (int r = 0; r < 4; ++r) {     // A-frag = astat * E[col], truncated to bf16
      au[r]     = pk2(astat[2 * r + 1] * e0, astat[2 * r] * e0);
      au[4 + r] = pk2(astat[8 + 2 * r + 1] * e0, astat[8 + 2 * r] * e0);
    }
    bf16x8 alo = mkbf(au[0], au[1], au[2], au[3]);
    bf16x8 ahi = mkbf(au[4], au[5], au[6], au[7]);
    bf16x8 qlo = mkbf(q[0], q[1], q[2], q[3]);
    bf16x8 qhi = mkbf(q[4], q[5], q[6], q[7]);
    acc = __builtin_amdgcn_mfma_f32_32x32x16_bf16(alo, qlo, z, 0, 0, 0);
    acc = __builtin_amdgcn_mfma_f32_32x32x16_bf16(ahi, qhi, acc, 0, 0, 0);
    #pragma unroll
    for (int r = 0; r < 4; ++r) {     // D regs -> next B-frag, in-lane repack only
      q[r]     = pk2(acc[2 * r + 1], acc[2 * r]);
      q[4 + r] = pk2(acc[8 + 2 * r + 1], acc[8 + 2 * r]);
    }
  };
  auto renorm = [&]() {               // exact power-of-2 renormalization
    float m = acc[0];
    #pragma unroll
    for (int r = 1; r < 16; ++r) m = fmaxf(m, acc[r]);
    #pragma unroll
    for (int mk = 1; mk <= 32; mk <<= 1) m = fmaxf(m, __shfl_xor(m, mk));
    int ex;
    frexpf(m, &ex);
    float sc = ldexpf(1.0f, -ex);
    eacc += ex;
    #pragma unroll
    for (int r = 0; r < 16; ++r) acc[r] *= sc;
    #pragma unroll
    for (int r = 0; r < 4; ++r) {     // re-pack q from renormalized acc
      q[r]     = pk2(acc[2 * r + 1], acc[2 * r]);
      q[4 + r] = pk2(acc[8 + 2 * r + 1], acc[8 + 2 * r]);
    }
  };

  uint4 ev = *(const uint4*)(Eb);     // group 0 (8 steps of E, 16B)
  int gstart = 0;
  if (c == 0) {                       // t=0 is the prior step: skip it
    uint4 evn = *(const uint4*)(Eb + 8);
    #pragma unroll
    for (int j = 1; j < 8; ++j) {
      uint32_t u = ((const uint32_t*)&ev)[j >> 1];
      step(bf2f((j & 1) ? (ushort)(u >> 16) : (ushort)(u & 0xFFFF)));
    }
    renorm();
    ev = evn;
    gstart = 1;
  }
  for (int g = gstart; g < CH_ / 8; ++g) {
    uint4 evn;
    if (g < CH_ / 8 - 1) evn = *(const uint4*)(Eb + 8 * (g + 1));  // prefetch next group
    #pragma unroll
    for (int j = 0; j < 8; ++j) {
      uint32_t u = ((const uint32_t*)&ev)[j >> 1];
      step(bf2f((j & 1) ? (ushort)(u >> 16) : (ushort)(u & 0xFFFF)));
    }
    renorm();
    ev = evn;
  }
  float* Qout = ws + WS_Q + (size_t)bc * (K_ * K_);
  #pragma unroll
  for (int r = 0; r < 16; ++r) {      // store un-permuted: row = pi(physical row)
    int m_ = (r & 3) + 8 * (r >> 2) + 4 * h;
    Qout[perm_r(m_) * K_ + n] = acc[r];
  }
  if (l == 0) ((int*)ws)[WS_EACC + bc] = eacc;
}

// ---------------- phase 2: MFMA tree-combine of 128 chunk matrices per b ----------------
// 8 waves/block: wave w composes its 16 chunk matrices via the same A-frag/B-frag
// MFMA primitive as chunk_kernel (B starts at identity; A-frag ring FULLY UNROLLED so
// it stays in VGPRs — R6's rolled ring was demoted to scratch, VGPR_Count=36 proved it).
// Then LDS exchange and wave 0 composes the 8 partials + applies alpha0.
__global__ __launch_bounds__(512) void combine_kernel(float* __restrict__ ws,
                                                      float* __restrict__ out) {
  __shared__ float pm[8][32 * 34];   // 8 partial matrices, row stride 34 (bank-safe, 8B-aligned)
  __shared__ int   pe[8];
  int tid = threadIdx.x;
  int l = tid & 63, w = tid >> 6;
  int h = l >> 5, n = l & 31;
  int b = blockIdx.x;
  int row = perm_r(n);
  const float* Qb = ws + WS_Q + (size_t)b * (F_ * K_ * K_);
  // early independent loads (latency overlapped with stage-1 compute)
  const ushort* Ew = (const ushort*)(ws + WS_E);
  float alpha0 = 0.0f, msm = 0.0f;
  if (w == 0) {
    alpha0 = ws[WS_PI + n] * bf2f(Ew[(size_t)(b * K_ + n) * T_]);   // both halves same
    msm = ws[WS_MS + b * 128 + l] + ws[WS_MS + b * 128 + 64 + l];
  }
  // chunk-exponent sum for this wave's 16 chunks
  int eacc = 0;
  {
    const int* ea = ((const int*)ws) + WS_EACC + b * F_ + w * 16;
    int v = (l < 16) ? ea[l] : 0;
    #pragma unroll
    for (int mk = 1; mk <= 8; mk <<= 1) v += __shfl_xor(v, mk);
    eacc = __shfl(v, 0);
  }
  // B-frag = identity
  uint32_t q[8];
  #pragma unroll
  for (int r = 0; r < 4; ++r) {
    int s0 = 8 * h + 2 * r;
    uint32_t lo = (s0 == n)     ? 0x3F80u : 0u;
    uint32_t hi = (s0 + 1 == n) ? 0x3F80u : 0u;
    q[r] = lo | (hi << 16);
    int s2 = s0 + 16;
    lo = (s2 == n)     ? 0x3F80u : 0u;
    hi = (s2 + 1 == n) ? 0x3F80u : 0u;
    q[4 + r] = lo | (hi << 16);
  }
  f32x16 acc;
  #pragma unroll
  for (int r = 0; r < 16; ++r) acc[r] = 0.0f;
  const f32x16 z = {0.f,0.f,0.f,0.f,0.f,0.f,0.f,0.f,0.f,0.f,0.f,0.f,0.f,0.f,0.f,0.f};

  // left-multiply helper: a[0..7] = M[row][8h+j], a[8..15] = M[row][16+8h+j]
  auto lmul = [&](const float* a) {
    uint32_t au[8];
    #pragma unroll
    for (int r = 0; r < 4; ++r) {
      au[r]     = pk2(a[2 * r + 1], a[2 * r]);
      au[4 + r] = pk2(a[8 + 2 * r + 1], a[8 + 2 * r]);
    }
    bf16x8 alo = mkbf(au[0], au[1], au[2], au[3]);
    bf16x8 ahi = mkbf(au[4], au[5], au[6], au[7]);
    bf16x8 qlo = mkbf(q[0], q[1], q[2], q[3]);
    bf16x8 qhi = mkbf(q[4], q[5], q[6], q[7]);
    acc = __builtin_amdgcn_mfma_f32_32x32x16_bf16(alo, qlo, z, 0, 0, 0);
    acc = __builtin_amdgcn_mfma_f32_32x32x16_bf16(ahi, qhi, acc, 0, 0, 0);
    #pragma unroll
    for (int r = 0; r < 4; ++r) {
      q[r]     = pk2(acc[2 * r + 1], acc[2 * r]);
      q[4 + r] = pk2(acc[8 + 2 * r + 1], acc[8 + 2 * r]);
    }
  };
  auto renorm = [&]() {
    float m = acc[0];
    #pragma unroll
    for (int r = 1; r < 16; ++r) m = fmaxf(m, acc[r]);
    #pragma unroll
    for (int mk = 1; mk <= 32; mk <<= 1) m = fmaxf(m, __shfl_xor(m, mk));
    int ex;
    frexpf(m, &ex);
    float sc = ldexpf(1.0f, -ex);
    eacc += ex;
    #pragma unroll
    for (int r = 0; r < 16; ++r) acc[r] *= sc;
    #pragma unroll
    for (int r = 0; r < 4; ++r) {
      q[r]     = pk2(acc[2 * r + 1], acc[2 * r]);
      q[4 + r] = pk2(acc[8 + 2 * r + 1], acc[8 + 2 * r]);
    }
  };

  // stage 1: compose this wave's 16 chunk matrices (ascending c => later chunks on the left)
  float4 ring[4][4];                 // depth-4 A-frag ring — static indices only
  #pragma unroll
  for (int p = 0; p < 4; ++p) {
    const float* Mc = Qb + (size_t)(w * 16 + p) * 1024 + row * 32;
    ring[p][0] = *(const float4*)(Mc + 8 * h);
    ring[p][1] = *(const float4*)(Mc + 8 * h + 4);
    ring[p][2] = *(const float4*)(Mc + 16 + 8 * h);
    ring[p][3] = *(const float4*)(Mc + 16 + 8 * h + 4);
  }
  #pragma unroll
  for (int c = 0; c < 16; ++c) {
    float a[16];
    #pragma unroll
    for (int j = 0; j < 16; ++j) a[j] = ((const float*)&ring[c & 3][0])[j];
    lmul(a);
    if (c + 4 < 16) {                // refill the slot just consumed
      const float* Mc = Qb + (size_t)(w * 16 + c + 4) * 1024 + row * 32;
      ring[c & 3][0] = *(const float4*)(Mc + 8 * h);
      ring[c & 3][1] = *(const float4*)(Mc + 8 * h + 4);
      ring[c & 3][2] = *(const float4*)(Mc + 16 + 8 * h);
      ring[c & 3][3] = *(const float4*)(Mc + 16 + 8 * h + 4);
    }
    if ((c & 3) == 3) renorm();
  }
  // publish partial product (D-layout -> plain matrix, padded rows)
  #pragma unroll
  for (int r = 0; r < 16; ++r) {
    int m_ = (r & 3) + 8 * (r >> 2) + 4 * h;
    pm[w][perm_r(m_) * 34 + n] = acc[r];
  }
  if (l == 0) pe[w] = eacc;
  __syncthreads();

  // stage 2: wave 0 composes the 8 partials (no renorm: drift <= 2^±40, fp32-safe)
  if (w == 0) {
    // reset B-frag to identity
    #pragma unroll
    for (int r = 0; r < 4; ++r) {
      int s0 = 8 * h + 2 * r;
      uint32_t lo = (s0 == n)     ? 0x3F80u : 0u;
      uint32_t hi = (s0 + 1 == n) ? 0x3F80u : 0u;
      q[r] = lo | (hi << 16);
      int s2 = s0 + 16;
      lo = (s2 == n)     ? 0x3F80u : 0u;
      hi = (s2 + 1 == n) ? 0x3F80u : 0u;
      q[4 + r] = lo | (hi << 16);
    }
    #pragma unroll
    for (int p = 0; p < 8; ++p) {
      float a[16];
      const float* base = &pm[p][row * 34];
      #pragma unroll
      for (int j = 0; j < 8; ++j) {
        a[j]     = base[8 * h + j];
        a[8 + j] = base[16 + 8 * h + j];
      }
      lmul(a);
    }
    int et = (l < 8) ? pe[l] : 0;
    #pragma unroll
    for (int mk = 1; mk <= 4; mk <<= 1) et += __shfl_xor(et, mk);
    et = __shfl(et, 0);
    // ssum = sum_{k,j} Qtot[k][j] * alpha0[j]; lane holds col n, rows across (r,h)
    float part = 0.0f;
    #pragma unroll
    for (int r = 0; r < 16; ++r) part += acc[r];
    part *= alpha0;
    #pragma unroll
    for (int mk = 1; mk <= 32; mk <<= 1) part += __shfl_xor(part, mk);
    #pragma unroll
    for (int mk = 32; mk; mk >>= 1) msm += __shfl_xor(msm, mk);
    if (l == 0) {
      float res = logf(part) + (float)et * 0.69314718055994531f + msm;
      atomicAdd(out, res);
    }
  }
}

extern "C" void kernel_launch(void* const* d_in, const int* in_sizes, int n_in,
                              void* d_out, int out_size, void* d_ws, size_t ws_size,
                              hipStream_t stream) {
  (void)in_sizes; (void)n_in; (void)out_size; (void)ws_size;
  const float* X      = (const float*)d_in[0];
  const float* priors = (const float*)d_in[1];
  const float* trans  = (const float*)d_in[2];
  const float* mu     = (const float*)d_in[3];
  const float* lv     = (const float*)d_in[4];
  float* ws  = (float*)d_ws;
  float* out = (float*)d_out;
  hipMemsetAsync(out, 0, sizeof(float), stream);
  prep_kernel<<<1, 1024, 0, stream>>>(priors, trans, mu, lv, ws);
  emis_kernel<<<2048, 256, 0, stream>>>(X, ws);
  chunk_kernel<<<B_ * F_ / 2, 128, 0, stream>>>(ws);
  combine_kernel<<<B_, 512, 0, stream>>>(ws, out);
}